// Round 10
// baseline (185.225 us; speedup 1.0000x reference)
//
#include <hip/hip_runtime.h>
#include <hip/hip_bf16.h>

typedef __attribute__((ext_vector_type(8))) short short8;
typedef __attribute__((ext_vector_type(4))) float f32x4;
typedef __attribute__((ext_vector_type(4))) unsigned short us4;

#define MFMA(a, b, c) __builtin_amdgcn_mfma_f32_16x16x32_bf16((a), (b), (c), 0, 0, 0)
#define EXP2(x) __builtin_amdgcn_exp2f(x)

static __device__ inline unsigned short f2b(float f) {
    __hip_bfloat16 h = __float2bfloat16(f);
    return *reinterpret_cast<unsigned short*>(&h);
}
static __device__ inline float b2f(unsigned short u) {
    unsigned int x = ((unsigned int)u) << 16;
    return __builtin_bit_cast(float, x);
}

// async global->LDS, 16B per lane. LDS dst must be wave-uniform base; HW adds lane*16.
static __device__ __forceinline__ void gload_lds16(const unsigned short* g, unsigned short* s) {
    __builtin_amdgcn_global_load_lds(
        (const __attribute__((address_space(1))) unsigned int*)(g),
        (__attribute__((address_space(3))) unsigned int*)(s),
        16, 0, 0);
}
#define WAITV(N) asm volatile("s_waitcnt vmcnt(" #N ")" ::: "memory")
#define WAITL    asm volatile("s_waitcnt lgkmcnt(0)" ::: "memory")
#define SBAR     __builtin_amdgcn_s_barrier()
#define SCHED0   __builtin_amdgcn_sched_barrier(0)

// ---------------- f32 -> bf16 conversion (weights only) ----------------
__global__ __launch_bounds__(256) void convk(
    const float* __restrict__ i0, const float* __restrict__ i1,
    const float* __restrict__ i2, const float* __restrict__ i3,
    unsigned short* o0, unsigned short* o1, unsigned short* o2, unsigned short* o3, int n)
{
    const float* in; unsigned short* out;
    switch (blockIdx.y) {
        case 0: in = i0; out = o0; break;
        case 1: in = i1; out = o1; break;
        case 2: in = i2; out = o2; break;
        default: in = i3; out = o3; break;
    }
    int i = (blockIdx.x * 256 + threadIdx.x) * 4;
    if (i >= n) return;
    float4 v = *(const float4*)(in + i);
    us4 o;
    o[0] = f2b(v.x); o[1] = f2b(v.y); o[2] = f2b(v.z); o[3] = f2b(v.w);
    *(us4*)(out + i) = o;
}

// ======== fused-convert QKV GEMM: C = f32A * bf16B^T + bias ========
// BM=64, BN=128, BK=32, 256 thr (4 waves 2x2, 8 MFMA/K-step/wave).
// A f32 -> regs -> convert -> ds_write; B via global_load_lds. 3 LDS bufs
// (36 KB -> 4 blocks/CU), counted vmcnt, 2-deep prefetch.
// Queue invariant at loop head: {B(t):2, A(t+1):2, B(t+1):2}.
__global__ __launch_bounds__(256) void gemm_qkv(
    const float* __restrict__ Aq, const float* __restrict__ Ak, const float* __restrict__ Av,
    const unsigned short* __restrict__ wq, const unsigned short* __restrict__ wk,
    const unsigned short* __restrict__ wv,
    const float* __restrict__ bq, const float* __restrict__ bk, const float* __restrict__ bv,
    unsigned short* __restrict__ qh, unsigned short* __restrict__ kh,
    unsigned short* __restrict__ vt,
    int M, int N, int K)
{
    __shared__ unsigned short sA[3][64 * 32];     // [buf][row][32]
    __shared__ unsigned short sB[3][128 * 32];

    // dispatch decode: 8 N-tiles of one (m,z) A-tile on the same XCD slot class
    const int d  = blockIdx.x;         // 0..1535
    const int c  = d & 7;
    const int t0 = d >> 3;             // 0..191
    const int nn = t0 & 7;
    const int g  = (t0 >> 3) * 8 + c;  // 0..191
    const int z  = g >> 6;             // 0..2
    const int mm = g & 63;

    const float* A           = z == 0 ? Aq : z == 1 ? Ak : Av;
    const unsigned short* Bm = z == 0 ? wq : z == 1 ? wk : wv;
    const float* bias        = z == 0 ? bq : z == 1 ? bk : bv;
    unsigned short* Cb       = z == 0 ? qh : z == 1 ? kh : vt;
    const int emode          = z == 2 ? 2 : 1;

    const int tid = threadIdx.x;
    const int wave = tid >> 6, lane = tid & 63;
    const int wm = (wave >> 1) * 32, wn = (wave & 1) * 64;
    const int bm = mm * 64, bn = nn * 128;
    const int fr = lane & 15, fg = lane >> 4;

    // A staging: thread -> row = tid>>2, 8 f32 at col (tid&3)*8
    const int ar = tid >> 2, ac = (tid & 3) * 8;
    const float* Ag = A + (size_t)(bm + ar) * K + ac;
    // B staging: per wave 2 gloads (16 rows each)
    const unsigned short* Bg = Bm + (size_t)(bn + wave * 32 + (lane >> 2)) * K + (lane & 3) * 8;

    f32x4 acc[2][4] = {};
    const int nt = K >> 5;                            // 32

    float4 rA[2];
    #define LOAD_A(t)  { const float* p = Ag + ((t) << 5); \
        rA[0] = *(const float4*)(p); rA[1] = *(const float4*)(p + 4); }
    #define GLOAD_B(buf, t) { const unsigned short* p = Bg + ((t) << 5); \
        gload_lds16(p,          &sB[buf][(wave * 32 + 0 ) * 32]); \
        gload_lds16(p + 16 * K, &sB[buf][(wave * 32 + 16) * 32]); }
    #define WRITE_A(buf) { \
        unsigned short* dsts = &sA[buf][ar * 32 + ac]; \
        us4 w0, w1; \
        w0[0] = f2b(rA[0].x); w0[1] = f2b(rA[0].y); w0[2] = f2b(rA[0].z); w0[3] = f2b(rA[0].w); \
        w1[0] = f2b(rA[1].x); w1[1] = f2b(rA[1].y); w1[2] = f2b(rA[1].z); w1[3] = f2b(rA[1].w); \
        *(us4*)(dsts) = w0; *(us4*)(dsts + 4) = w1; }

    // prologue
    LOAD_A(0);
    SCHED0;
    GLOAD_B(0, 0);                 // queue: {A0:2, B0:2}
    WAITV(2);                      // A0 landed
    WRITE_A(0);
    LOAD_A(1);
    SCHED0;
    GLOAD_B(1, 1);                 // queue: {B0:2, A1:2, B1:2} == invariant

    for (int t = 0; t < nt; ++t) {
        const int cur = t % 3;
        if (t + 1 < nt) { WAITV(2); } else { WAITV(0); }   // retire B(t) + A(t+1)
        if (t + 1 < nt) { WRITE_A((t + 1) % 3); }
        if (t + 2 < nt) {
            LOAD_A(t + 2);                                 // A before B (queue order)
            SCHED0;
            GLOAD_B((t + 2) % 3, t + 2);
        }
        WAITL;
        SBAR; SCHED0;               // tile t fully staged

        short8 af[2], bf[4];
        #pragma unroll
        for (int mr = 0; mr < 2; ++mr)
            af[mr] = *(const short8*)&sA[cur][(wm + mr * 16 + fr) * 32 + fg * 8];
        #pragma unroll
        for (int nr = 0; nr < 4; ++nr)
            bf[nr] = *(const short8*)&sB[cur][(wn + nr * 16 + fr) * 32 + fg * 8];
        #pragma unroll
        for (int mr = 0; mr < 2; ++mr)
            #pragma unroll
            for (int nr = 0; nr < 4; ++nr)
                acc[mr][nr] = MFMA(af[mr], bf[nr], acc[mr][nr]);

        SCHED0; SBAR;               // reads done before buf re-staged
    }

    #pragma unroll
    for (int mr = 0; mr < 2; ++mr)
        #pragma unroll
        for (int nr = 0; nr < 4; ++nr)
            #pragma unroll
            for (int j = 0; j < 4; ++j) {
                int m = bm + wm + mr * 16 + fg * 4 + j;
                int n = bn + wn + nr * 16 + fr;
                float v = acc[mr][nr][j] + bias[n];
                int b = m >> 10, s = m & 1023, h = n >> 6, dc = n & 63;
                if (emode == 1)
                    Cb[(((size_t)(b * 16 + h)) * 1024 + s) * 64 + dc] = f2b(v);
                else
                    Cb[(((size_t)(b * 16 + h)) * 64 + dc) * 1024 + s] = f2b(v);
            }
    #undef LOAD_A
    #undef GLOAD_B
    #undef WRITE_A
}

// ======== Wo GEMM: bf16 A (ctx), all-gload, BK=32, 3 bufs, counted vmcnt ========
__global__ __launch_bounds__(256) void gemm_wo(
    const unsigned short* __restrict__ A, const unsigned short* __restrict__ Bm,
    const float* __restrict__ bias, float* __restrict__ Cf, int M, int N, int K)
{
    __shared__ unsigned short sA[3][64 * 32];
    __shared__ unsigned short sB[3][128 * 32];

    const int d  = blockIdx.x;        // 0..511
    const int c  = d & 7;
    const int t0 = d >> 3;
    const int nn = t0 & 7;
    const int mm = (t0 >> 3) * 8 + c;

    const int tid = threadIdx.x;
    const int wave = tid >> 6, lane = tid & 63;
    const int wm = (wave >> 1) * 32, wn = (wave & 1) * 64;
    const int bm = mm * 64, bn = nn * 128;
    const int fr = lane & 15, fg = lane >> 4;

    const unsigned short* Ag = A + (size_t)(bm + wave * 16 + (lane >> 2)) * K + (lane & 3) * 8;
    const unsigned short* Bg = Bm + (size_t)(bn + wave * 32 + (lane >> 2)) * K + (lane & 3) * 8;

    #define STAGE(buf, t) { \
        gload_lds16(Ag + ((t) << 5),          &sA[buf][(wave * 16) * 32]); \
        const unsigned short* bp = Bg + ((t) << 5); \
        gload_lds16(bp,          &sB[buf][(wave * 32 + 0 ) * 32]); \
        gload_lds16(bp + 16 * K, &sB[buf][(wave * 32 + 16) * 32]); }

    f32x4 acc[2][4] = {};
    const int nt = K >> 5;

    STAGE(0, 0); STAGE(1, 1);       // queue: {t0:3, t1:3}
    for (int t = 0; t < nt; ++t) {
        const int cur = t % 3;
        if (t + 2 < nt)      { STAGE((t + 2) % 3, t + 2); WAITV(6); }  // retire tile t
        else if (t + 1 < nt) { WAITV(3); }                             // t == nt-2
        else                 { WAITV(0); }                             // t == nt-1
        SBAR; SCHED0;

        short8 af[2], bf[4];
        #pragma unroll
        for (int mr = 0; mr < 2; ++mr)
            af[mr] = *(const short8*)&sA[cur][(wm + mr * 16 + fr) * 32 + fg * 8];
        #pragma unroll
        for (int nr = 0; nr < 4; ++nr)
            bf[nr] = *(const short8*)&sB[cur][(wn + nr * 16 + fr) * 32 + fg * 8];
        #pragma unroll
        for (int mr = 0; mr < 2; ++mr)
            #pragma unroll
            for (int nr = 0; nr < 4; ++nr)
                acc[mr][nr] = MFMA(af[mr], bf[nr], acc[mr][nr]);

        SCHED0; SBAR;
    }
    #undef STAGE

    #pragma unroll
    for (int mr = 0; mr < 2; ++mr)
        #pragma unroll
        for (int nr = 0; nr < 4; ++nr)
            #pragma unroll
            for (int j = 0; j < 4; ++j) {
                int m = bm + wm + mr * 16 + fg * 4 + j;
                int n = bn + wn + nr * 16 + fr;
                Cf[(size_t)m * N + n] = acc[mr][nr][j] + bias[n];
            }
}

// ---------------- fused forget-attention (exp2-folded) ----------------
// Strip stores u = s*log2(e); all exponentials via v_exp_f32 (exp2) directly:
// e = 2^u = exp(s); te = 2^(-ag2*dist) = exp(-ag*dist); e2 = 2^(u*te) = exp(s*te).
__global__ __launch_bounds__(256) void attn_fused(
    const unsigned short* __restrict__ Qh,   // [BH,S,64] bf16
    const unsigned short* __restrict__ Kh,   // [BH,S,64] bf16
    const unsigned short* __restrict__ Vt,   // [BH,64,S] bf16
    const float* __restrict__ gammas,        // [16]
    float* __restrict__ attn_out,            // [BH,S,S] f32
    unsigned short* __restrict__ ctx)        // [B*S,1024] bf16
{
    extern __shared__ char smem[];
    const int RS = 1032;                     // bf16 row stride
    unsigned short* s_s = (unsigned short*)smem;                       // [16][1032] u -> e2
    unsigned short* s_q = (unsigned short*)(smem + 16 * RS * 2);       // [16][72]
    float* s_inv = (float*)(smem + 16 * RS * 2 + 16 * 72 * 2);         // [16]
    const int S = 1024;

    int gid = blockIdx.y * gridDim.x + blockIdx.x;     // 0..4095
    int jj = gid >> 3;
    const int bh = (gid & 7) * 8 + (jj >> 6);
    const int qb = jj & 63;
    const int q0 = qb * 16;
    const int tid = threadIdx.x;
    const int wave = tid >> 6, lane = tid & 63, fr = lane & 15, fg = lane >> 4;

    {
        int rr = tid >> 4, c4 = (tid & 15) * 4;
        *(uint2*)&s_q[rr * 72 + c4] = *(const uint2*)&Qh[((size_t)bh * S + q0 + rr) * 64 + c4];
    }
    __syncthreads();
    const int kmax = q0 + 15;

    // phase 1: u = (QK^T/8)*log2e -> bf16 strip (16-col tiles interleaved across waves)
    {
        short8 qf0 = *(const short8*)&s_q[fr * 72 + fg * 8];
        short8 qf1 = *(const short8*)&s_q[fr * 72 + 32 + fg * 8];
        const unsigned short* kbase = &Kh[(size_t)bh * S * 64];
        for (int nf = 0; nf < 16; ++nf) {
            int cb = (nf * 4 + wave) * 16;
            if (cb > kmax) break;
            const unsigned short* kb = kbase + (size_t)cb * 64;
            short8 kf0 = *(const short8*)&kb[fr * 64 + fg * 8];
            short8 kf1 = *(const short8*)&kb[fr * 64 + 32 + fg * 8];
            f32x4 a = {0.f, 0.f, 0.f, 0.f};
            a = MFMA(qf0, kf0, a);
            a = MFMA(qf1, kf1, a);
            #pragma unroll
            for (int j = 0; j < 4; ++j)
                s_s[(size_t)(fg * 4 + j) * RS + cb + fr] = f2b(a[j] * 0.18033688f);
        }
    }
    __syncthreads();

    // phase 2: fused softmax->cumsum->decay on contiguous per-lane segments
    {
        const int r = tid >> 4, sub = tid & 15;
        const int qr = q0 + r;
        unsigned short* srow = &s_s[(size_t)r * RS];
        const float ag2 = fabsf(gammas[bh & 15]) * 1.44269504f;
        const int m = ((qb + 4) >> 2) | 1;     // ceil((qb+1)/4), forced odd
        const int L = 4 * m;
        const int base = sub * L;

        float seg = 0.f;
        for (int c = 0; c < m; ++c) {
            us4 s4 = *(const us4*)&srow[base + c * 4];
            #pragma unroll
            for (int j = 0; j < 4; ++j) {
                int kk = base + c * 4 + j;
                seg += (kk <= qr) ? EXP2(b2f(s4[j])) : 0.f;
            }
        }
        float x = seg, t;
        t = __shfl_up(x, 1, 16); if (sub >= 1) x += t;
        t = __shfl_up(x, 2, 16); if (sub >= 2) x += t;
        t = __shfl_up(x, 4, 16); if (sub >= 4) x += t;
        t = __shfl_up(x, 8, 16); if (sub >= 8) x += t;
        const float T = __shfl(x, 15, 16);
        const float invT = 1.f / T;
        float run = x - seg;

        float ls2 = 0.f;
        for (int c = 0; c < m; ++c) {
            us4 s4 = *(const us4*)&srow[base + c * 4];
            us4 o;
            #pragma unroll
            for (int j = 0; j < 4; ++j) {
                int kk = base + c * 4 + j;
                bool act = kk <= qr;
                float u = b2f(s4[j]);
                float e = act ? EXP2(u) : 0.f;
                run += e;
                float rem = fmaxf(T - run, 0.f) * invT;
                float dist = sqrtf(rem * (float)(qr - kk));
                float te = EXP2(-ag2 * dist);
                float e2 = act ? EXP2(u * te) : 0.f;
                o[j] = f2b(e2);
                ls2 += e2;
            }
            *(us4*)&srow[base + c * 4] = o;
        }
        us4 z = {0, 0, 0, 0};
        for (int c = 4 * L + sub; c < 256; c += 16)
            *(us4*)&srow[c * 4] = z;
        #pragma unroll
        for (int mm = 1; mm < 16; mm <<= 1) ls2 += __shfl_xor(ls2, mm, 16);
        if (sub == 0) s_inv[r] = 1.f / ls2;
    }
    __syncthreads();

    // phase 2b: attn write-out (barrier-free; overlaps phase 3's MFMA)
    for (int r2 = 0; r2 < 16; ++r2) {
        us4 e4 = *(const us4*)&s_s[(size_t)r2 * RS + tid * 4];
        float iv = s_inv[r2];
        f32x4 w = {b2f(e4[0]) * iv, b2f(e4[1]) * iv, b2f(e4[2]) * iv, b2f(e4[3]) * iv};
        __builtin_nontemporal_store(w,
            (f32x4*)(attn_out + ((size_t)bh * S + q0 + r2) * S + tid * 4));
    }

    // phase 3: ctx = (e2 @ V) * inv  (each wave: 16 d-columns)
    {
        const unsigned short* vb = &Vt[(size_t)bh * 64 * S];
        f32x4 acc = {0.f, 0.f, 0.f, 0.f};
        const int ktiles = (kmax + 32) >> 5;
        const unsigned short* prow = &s_s[(size_t)fr * RS];
        for (int kt = 0; kt < ktiles; ++kt) {
            short8 pa = *(const short8*)&prow[kt * 32 + fg * 8];
            short8 vf = *(const short8*)&vb[(size_t)(wave * 16 + fr) * S + kt * 32 + fg * 8];
            acc = MFMA(pa, vf, acc);
        }
        int b = bh >> 4, h = bh & 15;
        #pragma unroll
        for (int j = 0; j < 4; ++j) {
            float iv = s_inv[fg * 4 + j];
            ctx[((size_t)b * S + q0 + fg * 4 + j) * 1024 + h * 64 + wave * 16 + fr] = f2b(acc[j] * iv);
        }
    }
}

extern "C" void kernel_launch(void* const* d_in, const int* in_sizes, int n_in,
                              void* d_out, int out_size, void* d_ws, size_t ws_size,
                              hipStream_t stream) {
    const float* query  = (const float*)d_in[0];
    const float* key    = (const float*)d_in[1];
    const float* value  = (const float*)d_in[2];
    const float* Wq = (const float*)d_in[4];
    const float* bq = (const float*)d_in[5];
    const float* Wk = (const float*)d_in[6];
    const float* bk = (const float*)d_in[7];
    const float* Wv = (const float*)d_in[8];
    const float* bv = (const float*)d_in[9];
    const float* Wo = (const float*)d_in[10];
    const float* bo = (const float*)d_in[11];
    const float* gammas = (const float*)d_in[12];

    const int S = 1024, dmodel = 1024;
    const int M = 4 * S;
    const size_t MD = (size_t)M * dmodel;
    const size_t DD = (size_t)dmodel * dmodel;

    char* ws = (char*)d_ws;
    unsigned short* wqb = (unsigned short*)ws;            ws += DD * 2;
    unsigned short* wkb = (unsigned short*)ws;            ws += DD * 2;
    unsigned short* wvb = (unsigned short*)ws;            ws += DD * 2;
    unsigned short* wob = (unsigned short*)ws;            ws += DD * 2;
    unsigned short* qh  = (unsigned short*)ws;            ws += MD * 2;
    unsigned short* kh  = (unsigned short*)ws;            ws += MD * 2;
    unsigned short* vt  = (unsigned short*)ws;            ws += MD * 2;
    unsigned short* ctx = (unsigned short*)ws;            ws += MD * 2;

    float* outp = (float*)d_out;
    float* attn_out = outp + MD;

    // 1) weight conversions only
    convk<<<dim3(1024, 4), 256, 0, stream>>>(Wq, Wk, Wv, Wo, wqb, wkb, wvb, wob, (int)DD);

    // 2) fused-convert QKV projections (BK=32, 3-buf, 4 blocks/CU)
    gemm_qkv<<<dim3(1536), 256, 0, stream>>>(
        query, key, value, wqb, wkb, wvb, bq, bk, bv, qh, kh, vt, M, dmodel, dmodel);

    // 3) fused forget-attention
    size_t lds = 16 * 1032 * 2 + 16 * 72 * 2 + 16 * 4;   // 35,392 B -> 4 blocks/CU
    attn_fused<<<dim3(64, 64), 256, lds, stream>>>(qh, kh, vt, gammas, attn_out, ctx);

    // 4) output projection (BK=32, 3-buf, 4 blocks/CU)
    gemm_wo<<<dim3(512), 256, 0, stream>>>(ctx, wob, bo, outp, M, dmodel, dmodel);
}

// Round 11
// 175.184 us; speedup vs baseline: 1.0573x; 1.0573x over previous
//
#include <hip/hip_runtime.h>
#include <hip/hip_bf16.h>

typedef __attribute__((ext_vector_type(8))) short short8;
typedef __attribute__((ext_vector_type(4))) float f32x4;
typedef __attribute__((ext_vector_type(4))) unsigned short us4;

#define MFMA(a, b, c) __builtin_amdgcn_mfma_f32_16x16x32_bf16((a), (b), (c), 0, 0, 0)
#define EXP2(x) __builtin_amdgcn_exp2f(x)

static __device__ inline unsigned short f2b(float f) {
    __hip_bfloat16 h = __float2bfloat16(f);
    return *reinterpret_cast<unsigned short*>(&h);
}
static __device__ inline float b2f(unsigned short u) {
    unsigned int x = ((unsigned int)u) << 16;
    return __builtin_bit_cast(float, x);
}

// async global->LDS, 16B per lane. LDS dst must be wave-uniform base; HW adds lane*16.
static __device__ __forceinline__ void gload_lds16(const unsigned short* g, unsigned short* s) {
    __builtin_amdgcn_global_load_lds(
        (const __attribute__((address_space(1))) unsigned int*)(g),
        (__attribute__((address_space(3))) unsigned int*)(s),
        16, 0, 0);
}
#define WAITV(N) asm volatile("s_waitcnt vmcnt(" #N ")" ::: "memory")
#define WAITL    asm volatile("s_waitcnt lgkmcnt(0)" ::: "memory")
#define SBAR     __builtin_amdgcn_s_barrier()
#define SCHED0   __builtin_amdgcn_sched_barrier(0)

// ---------------- f32 -> bf16 conversion (weights only) ----------------
__global__ __launch_bounds__(256) void convk(
    const float* __restrict__ i0, const float* __restrict__ i1,
    const float* __restrict__ i2, const float* __restrict__ i3,
    unsigned short* o0, unsigned short* o1, unsigned short* o2, unsigned short* o3, int n)
{
    const float* in; unsigned short* out;
    switch (blockIdx.y) {
        case 0: in = i0; out = o0; break;
        case 1: in = i1; out = o1; break;
        case 2: in = i2; out = o2; break;
        default: in = i3; out = o3; break;
    }
    int i = (blockIdx.x * 256 + threadIdx.x) * 4;
    if (i >= n) return;
    float4 v = *(const float4*)(in + i);
    us4 o;
    o[0] = f2b(v.x); o[1] = f2b(v.y); o[2] = f2b(v.z); o[3] = f2b(v.w);
    *(us4*)(out + i) = o;
}

// ======== fused-convert QKV GEMM: C = f32A * bf16B^T + bias ========
// BM=128, BN=128, BK=32 (m97 geometry): 4 waves 2x2, each 64x64 out,
// 16 MFMA + 8 ds_read_b128 per wave per K-step. A f32 -> regs -> bf16 ->
// ds_write; B via global_load_lds. 3 LDS bufs (48 KB -> 3 blocks/CU),
// counted vmcnt 2-deep. Queue at loop head: {B(t):2, A(t+1):4, B(t+1):2}.
__global__ __launch_bounds__(256) void gemm_qkv(
    const float* __restrict__ Aq, const float* __restrict__ Ak, const float* __restrict__ Av,
    const unsigned short* __restrict__ wq, const unsigned short* __restrict__ wk,
    const unsigned short* __restrict__ wv,
    const float* __restrict__ bq, const float* __restrict__ bk, const float* __restrict__ bv,
    unsigned short* __restrict__ qh, unsigned short* __restrict__ kh,
    unsigned short* __restrict__ vt,
    int M, int N, int K)
{
    __shared__ unsigned short sA[3][128 * 32];
    __shared__ unsigned short sB[3][128 * 32];

    // decode: 8 N-tiles of one (m,z) A-tile on consecutive same-XCD slots
    const int d  = blockIdx.x;         // 0..767
    const int c  = d & 7;
    const int t0 = d >> 3;             // 0..95
    const int nn = t0 & 7;
    const int g  = (t0 >> 3) * 8 + c;  // 0..95
    const int z  = g >> 5;             // 0..2
    const int mm = g & 31;

    const float* A           = z == 0 ? Aq : z == 1 ? Ak : Av;
    const unsigned short* Bm = z == 0 ? wq : z == 1 ? wk : wv;
    const float* bias        = z == 0 ? bq : z == 1 ? bk : bv;
    unsigned short* Cb       = z == 0 ? qh : z == 1 ? kh : vt;
    const int emode          = z == 2 ? 2 : 1;

    const int tid = threadIdx.x;
    const int wave = tid >> 6, lane = tid & 63;
    const int wm = (wave >> 1) * 64, wn = (wave & 1) * 64;
    const int bm = mm * 128, bn = nn * 128;
    const int fr = lane & 15, fg = lane >> 4;

    // A staging: thread -> row = tid>>1 (0..127), 16 f32 at col (tid&1)*16
    const int ar = tid >> 1, ac = (tid & 1) * 16;
    const float* Ag = A + (size_t)(bm + ar) * K + ac;
    // B staging: per wave 2 gloads (16 rows each) over the wave's 32-row span
    const unsigned short* Bg = Bm + (size_t)(bn + wave * 32 + (lane >> 2)) * K + (lane & 3) * 8;

    f32x4 acc[4][4] = {};
    const int nt = K >> 5;                            // 32

    float4 rA[4];
    #define LOAD_A(t)  { const float* p = Ag + ((t) << 5); \
        rA[0] = *(const float4*)(p);     rA[1] = *(const float4*)(p + 4); \
        rA[2] = *(const float4*)(p + 8); rA[3] = *(const float4*)(p + 12); }
    #define GLOAD_B(buf, t) { const unsigned short* p = Bg + ((t) << 5); \
        gload_lds16(p,          &sB[buf][(wave * 32 + 0 ) * 32]); \
        gload_lds16(p + 16 * K, &sB[buf][(wave * 32 + 16) * 32]); }
    #define WRITE_A(buf) { \
        unsigned short* dsts = &sA[buf][ar * 32 + ac]; \
        short8 w; \
        w[0] = (short)f2b(rA[0].x); w[1] = (short)f2b(rA[0].y); \
        w[2] = (short)f2b(rA[0].z); w[3] = (short)f2b(rA[0].w); \
        w[4] = (short)f2b(rA[1].x); w[5] = (short)f2b(rA[1].y); \
        w[6] = (short)f2b(rA[1].z); w[7] = (short)f2b(rA[1].w); \
        *(short8*)(dsts) = w; \
        w[0] = (short)f2b(rA[2].x); w[1] = (short)f2b(rA[2].y); \
        w[2] = (short)f2b(rA[2].z); w[3] = (short)f2b(rA[2].w); \
        w[4] = (short)f2b(rA[3].x); w[5] = (short)f2b(rA[3].y); \
        w[6] = (short)f2b(rA[3].z); w[7] = (short)f2b(rA[3].w); \
        *(short8*)(dsts + 8) = w; }

    // prologue
    LOAD_A(0);
    SCHED0;
    GLOAD_B(0, 0);                 // queue: {A0:4, B0:2}
    WAITV(2);                      // A0 landed (B0 outstanding)
    WRITE_A(0);
    LOAD_A(1);
    SCHED0;
    GLOAD_B(1, 1);                 // queue: {B0:2, A1:4, B1:2} == invariant

    for (int t = 0; t < nt; ++t) {
        const int cur = t % 3;
        if (t + 1 < nt) { WAITV(2); } else { WAITV(0); }   // retire B(t) + A(t+1)
        if (t + 1 < nt) { WRITE_A((t + 1) % 3); }
        if (t + 2 < nt) {
            LOAD_A(t + 2);                                 // A before B (queue order)
            SCHED0;
            GLOAD_B((t + 2) % 3, t + 2);
        }
        WAITL;
        SBAR; SCHED0;               // tile t fully staged

        short8 af[4], bf[4];
        #pragma unroll
        for (int mr = 0; mr < 4; ++mr)
            af[mr] = *(const short8*)&sA[cur][(wm + mr * 16 + fr) * 32 + fg * 8];
        #pragma unroll
        for (int nr = 0; nr < 4; ++nr)
            bf[nr] = *(const short8*)&sB[cur][(wn + nr * 16 + fr) * 32 + fg * 8];
        #pragma unroll
        for (int mr = 0; mr < 4; ++mr)
            #pragma unroll
            for (int nr = 0; nr < 4; ++nr)
                acc[mr][nr] = MFMA(af[mr], bf[nr], acc[mr][nr]);

        SCHED0; SBAR;               // reads done before buf re-staged
    }

    #pragma unroll
    for (int mr = 0; mr < 4; ++mr)
        #pragma unroll
        for (int nr = 0; nr < 4; ++nr)
            #pragma unroll
            for (int j = 0; j < 4; ++j) {
                int m = bm + wm + mr * 16 + fg * 4 + j;
                int n = bn + wn + nr * 16 + fr;
                float v = acc[mr][nr][j] + bias[n];
                int b = m >> 10, s = m & 1023, h = n >> 6, dc = n & 63;
                if (emode == 1)
                    Cb[(((size_t)(b * 16 + h)) * 1024 + s) * 64 + dc] = f2b(v);
                else
                    Cb[(((size_t)(b * 16 + h)) * 64 + dc) * 1024 + s] = f2b(v);
            }
    #undef LOAD_A
    #undef GLOAD_B
    #undef WRITE_A
}

// ======== Wo GEMM: bf16 A (ctx), all-gload, 128x128, BK=32, 3 bufs ========
// 4 gloads/iter/wave; steady WAITV(8) retires tile t; tail 4 -> 0.
__global__ __launch_bounds__(256) void gemm_wo(
    const unsigned short* __restrict__ A, const unsigned short* __restrict__ Bm,
    const float* __restrict__ bias, float* __restrict__ Cf, int M, int N, int K)
{
    __shared__ unsigned short sA[3][128 * 32];
    __shared__ unsigned short sB[3][128 * 32];

    const int d  = blockIdx.x;        // 0..255
    const int c  = d & 7;
    const int t0 = d >> 3;            // 0..31
    const int nn = t0 & 7;
    const int mm = (t0 >> 3) * 8 + c; // 0..31

    const int tid = threadIdx.x;
    const int wave = tid >> 6, lane = tid & 63;
    const int wm = (wave >> 1) * 64, wn = (wave & 1) * 64;
    const int bm = mm * 128, bn = nn * 128;
    const int fr = lane & 15, fg = lane >> 4;

    const unsigned short* Ag = A + (size_t)(bm + wave * 32 + (lane >> 2)) * K + (lane & 3) * 8;
    const unsigned short* Bg = Bm + (size_t)(bn + wave * 32 + (lane >> 2)) * K + (lane & 3) * 8;

    #define STAGE(buf, t) { \
        const unsigned short* ap = Ag + ((t) << 5); \
        gload_lds16(ap,          &sA[buf][(wave * 32 + 0 ) * 32]); \
        gload_lds16(ap + 16 * K, &sA[buf][(wave * 32 + 16) * 32]); \
        const unsigned short* bp = Bg + ((t) << 5); \
        gload_lds16(bp,          &sB[buf][(wave * 32 + 0 ) * 32]); \
        gload_lds16(bp + 16 * K, &sB[buf][(wave * 32 + 16) * 32]); }

    f32x4 acc[4][4] = {};
    const int nt = K >> 5;

    STAGE(0, 0); STAGE(1, 1);       // queue: {t0:4, t1:4}
    for (int t = 0; t < nt; ++t) {
        const int cur = t % 3;
        if (t + 2 < nt)      { STAGE((t + 2) % 3, t + 2); WAITV(8); }  // retire tile t
        else if (t + 1 < nt) { WAITV(4); }                             // t == nt-2
        else                 { WAITV(0); }                             // t == nt-1
        SBAR; SCHED0;

        short8 af[4], bf[4];
        #pragma unroll
        for (int mr = 0; mr < 4; ++mr)
            af[mr] = *(const short8*)&sA[cur][(wm + mr * 16 + fr) * 32 + fg * 8];
        #pragma unroll
        for (int nr = 0; nr < 4; ++nr)
            bf[nr] = *(const short8*)&sB[cur][(wn + nr * 16 + fr) * 32 + fg * 8];
        #pragma unroll
        for (int mr = 0; mr < 4; ++mr)
            #pragma unroll
            for (int nr = 0; nr < 4; ++nr)
                acc[mr][nr] = MFMA(af[mr], bf[nr], acc[mr][nr]);

        SCHED0; SBAR;
    }
    #undef STAGE

    #pragma unroll
    for (int mr = 0; mr < 4; ++mr)
        #pragma unroll
        for (int nr = 0; nr < 4; ++nr)
            #pragma unroll
            for (int j = 0; j < 4; ++j) {
                int m = bm + wm + mr * 16 + fg * 4 + j;
                int n = bn + wn + nr * 16 + fr;
                Cf[(size_t)m * N + n] = acc[mr][nr][j] + bias[n];
            }
}

// ---------------- fused forget-attention (phase-1 break-free, pipelineable) ----------------
__global__ __launch_bounds__(256) void attn_fused(
    const unsigned short* __restrict__ Qh,   // [BH,S,64] bf16
    const unsigned short* __restrict__ Kh,   // [BH,S,64] bf16
    const unsigned short* __restrict__ Vt,   // [BH,64,S] bf16
    const float* __restrict__ gammas,        // [16]
    float* __restrict__ attn_out,            // [BH,S,S] f32
    unsigned short* __restrict__ ctx)        // [B*S,1024] bf16
{
    extern __shared__ char smem[];
    const int RS = 1032;                     // bf16 row stride
    unsigned short* s_s = (unsigned short*)smem;                       // [16][1032] u -> e2
    unsigned short* s_q = (unsigned short*)(smem + 16 * RS * 2);       // [16][72]
    float* s_inv = (float*)(smem + 16 * RS * 2 + 16 * 72 * 2);         // [16]
    const int S = 1024;

    int gid = blockIdx.y * gridDim.x + blockIdx.x;     // 0..4095
    int jj = gid >> 3;
    const int bh = (gid & 7) * 8 + (jj >> 6);
    const int qb = jj & 63;
    const int q0 = qb * 16;
    const int tid = threadIdx.x;
    const int wave = tid >> 6, lane = tid & 63, fr = lane & 15, fg = lane >> 4;

    {
        int rr = tid >> 4, c4 = (tid & 15) * 4;
        *(uint2*)&s_q[rr * 72 + c4] = *(const uint2*)&Qh[((size_t)bh * S + q0 + rr) * 64 + c4];
    }
    __syncthreads();
    const int kmax = q0 + 15;

    // phase 1: u = (QK^T/8)*log2e -> bf16 strip. Break-free trip count so the
    // compiler can pipeline the global K loads across iterations.
    {
        short8 qf0 = *(const short8*)&s_q[fr * 72 + fg * 8];
        short8 qf1 = *(const short8*)&s_q[fr * 72 + 32 + fg * 8];
        const unsigned short* kbase = &Kh[(size_t)bh * S * 64];
        const int iters = (qb >= wave) ? (((qb - wave) >> 2) + 1) : 0;
        #pragma unroll 2
        for (int nf = 0; nf < iters; ++nf) {
            int cb = (nf * 4 + wave) * 16;
            const unsigned short* kb = kbase + (size_t)cb * 64;
            short8 kf0 = *(const short8*)&kb[fr * 64 + fg * 8];
            short8 kf1 = *(const short8*)&kb[fr * 64 + 32 + fg * 8];
            f32x4 a = {0.f, 0.f, 0.f, 0.f};
            a = MFMA(qf0, kf0, a);
            a = MFMA(qf1, kf1, a);
            #pragma unroll
            for (int j = 0; j < 4; ++j)
                s_s[(size_t)(fg * 4 + j) * RS + cb + fr] = f2b(a[j] * 0.18033688f);
        }
    }
    __syncthreads();

    // phase 2: fused softmax->cumsum->decay on contiguous per-lane segments
    {
        const int r = tid >> 4, sub = tid & 15;
        const int qr = q0 + r;
        unsigned short* srow = &s_s[(size_t)r * RS];
        const float ag2 = fabsf(gammas[bh & 15]) * 1.44269504f;
        const int m = ((qb + 4) >> 2) | 1;     // ceil((qb+1)/4), forced odd
        const int L = 4 * m;
        const int base = sub * L;

        float seg = 0.f;
        for (int c = 0; c < m; ++c) {
            us4 s4 = *(const us4*)&srow[base + c * 4];
            #pragma unroll
            for (int j = 0; j < 4; ++j) {
                int kk = base + c * 4 + j;
                seg += (kk <= qr) ? EXP2(b2f(s4[j])) : 0.f;
            }
        }
        float x = seg, t;
        t = __shfl_up(x, 1, 16); if (sub >= 1) x += t;
        t = __shfl_up(x, 2, 16); if (sub >= 2) x += t;
        t = __shfl_up(x, 4, 16); if (sub >= 4) x += t;
        t = __shfl_up(x, 8, 16); if (sub >= 8) x += t;
        const float T = __shfl(x, 15, 16);
        const float invT = 1.f / T;
        float run = x - seg;

        float ls2 = 0.f;
        for (int c = 0; c < m; ++c) {
            us4 s4 = *(const us4*)&srow[base + c * 4];
            us4 o;
            #pragma unroll
            for (int j = 0; j < 4; ++j) {
                int kk = base + c * 4 + j;
                bool act = kk <= qr;
                float u = b2f(s4[j]);
                float e = act ? EXP2(u) : 0.f;
                run += e;
                float rem = fmaxf(T - run, 0.f) * invT;
                float dist = sqrtf(rem * (float)(qr - kk));
                float te = EXP2(-ag2 * dist);
                float e2 = act ? EXP2(u * te) : 0.f;
                o[j] = f2b(e2);
                ls2 += e2;
            }
            *(us4*)&srow[base + c * 4] = o;
        }
        us4 z = {0, 0, 0, 0};
        for (int c = 4 * L + sub; c < 256; c += 16)
            *(us4*)&srow[c * 4] = z;
        #pragma unroll
        for (int mm = 1; mm < 16; mm <<= 1) ls2 += __shfl_xor(ls2, mm, 16);
        if (sub == 0) s_inv[r] = 1.f / ls2;
    }
    __syncthreads();

    // phase 2b: attn write-out (barrier-free; overlaps phase 3's MFMA)
    for (int r2 = 0; r2 < 16; ++r2) {
        us4 e4 = *(const us4*)&s_s[(size_t)r2 * RS + tid * 4];
        float iv = s_inv[r2];
        f32x4 w = {b2f(e4[0]) * iv, b2f(e4[1]) * iv, b2f(e4[2]) * iv, b2f(e4[3]) * iv};
        __builtin_nontemporal_store(w,
            (f32x4*)(attn_out + ((size_t)bh * S + q0 + r2) * S + tid * 4));
    }

    // phase 3: ctx = (e2 @ V) * inv  (each wave: 16 d-columns)
    {
        const unsigned short* vb = &Vt[(size_t)bh * 64 * S];
        f32x4 acc = {0.f, 0.f, 0.f, 0.f};
        const int ktiles = (kmax + 32) >> 5;
        const unsigned short* prow = &s_s[(size_t)fr * RS];
        #pragma unroll 2
        for (int kt = 0; kt < ktiles; ++kt) {
            short8 pa = *(const short8*)&prow[kt * 32 + fg * 8];
            short8 vf = *(const short8*)&vb[(size_t)(wave * 16 + fr) * S + kt * 32 + fg * 8];
            acc = MFMA(pa, vf, acc);
        }
        int b = bh >> 4, h = bh & 15;
        #pragma unroll
        for (int j = 0; j < 4; ++j) {
            float iv = s_inv[fg * 4 + j];
            ctx[((size_t)b * S + q0 + fg * 4 + j) * 1024 + h * 64 + wave * 16 + fr] = f2b(acc[j] * iv);
        }
    }
}

extern "C" void kernel_launch(void* const* d_in, const int* in_sizes, int n_in,
                              void* d_out, int out_size, void* d_ws, size_t ws_size,
                              hipStream_t stream) {
    const float* query  = (const float*)d_in[0];
    const float* key    = (const float*)d_in[1];
    const float* value  = (const float*)d_in[2];
    const float* Wq = (const float*)d_in[4];
    const float* bq = (const float*)d_in[5];
    const float* Wk = (const float*)d_in[6];
    const float* bk = (const float*)d_in[7];
    const float* Wv = (const float*)d_in[8];
    const float* bv = (const float*)d_in[9];
    const float* Wo = (const float*)d_in[10];
    const float* bo = (const float*)d_in[11];
    const float* gammas = (const float*)d_in[12];

    const int S = 1024, dmodel = 1024;
    const int M = 4 * S;
    const size_t MD = (size_t)M * dmodel;
    const size_t DD = (size_t)dmodel * dmodel;

    char* ws = (char*)d_ws;
    unsigned short* wqb = (unsigned short*)ws;            ws += DD * 2;
    unsigned short* wkb = (unsigned short*)ws;            ws += DD * 2;
    unsigned short* wvb = (unsigned short*)ws;            ws += DD * 2;
    unsigned short* wob = (unsigned short*)ws;            ws += DD * 2;
    unsigned short* qh  = (unsigned short*)ws;            ws += MD * 2;
    unsigned short* kh  = (unsigned short*)ws;            ws += MD * 2;
    unsigned short* vt  = (unsigned short*)ws;            ws += MD * 2;
    unsigned short* ctx = (unsigned short*)ws;            ws += MD * 2;

    float* outp = (float*)d_out;
    float* attn_out = outp + MD;

    // 1) weight conversions only
    convk<<<dim3(1024, 4), 256, 0, stream>>>(Wq, Wk, Wv, Wo, wqb, wkb, wvb, wob, (int)DD);

    // 2) fused-convert QKV projections (128x128 tile, 3-buf, counted vmcnt)
    gemm_qkv<<<dim3(768), 256, 0, stream>>>(
        query, key, value, wqb, wkb, wvb, bq, bk, bv, qh, kh, vt, M, dmodel, dmodel);

    // 3) fused forget-attention
    size_t lds = 16 * 1032 * 2 + 16 * 72 * 2 + 16 * 4;   // 35,392 B -> 4 blocks/CU
    attn_fused<<<dim3(64, 64), 256, lds, stream>>>(qh, kh, vt, gammas, attn_out, ctx);

    // 4) output projection (128x128 tile)
    gemm_wo<<<dim3(256), 256, 0, stream>>>(ctx, wob, bo, outp, M, dmodel, dmodel);
}